// Round 13
// baseline (102.050 us; speedup 1.0000x reference)
//
#include <hip/hip_runtime.h>
#include <hip/hip_bf16.h>

typedef __attribute__((ext_vector_type(8))) short short8;  // 8 bf16 (4 VGPRs)
typedef __attribute__((ext_vector_type(4))) short short4v;
typedef __attribute__((ext_vector_type(4))) float f32x4;
typedef __attribute__((ext_vector_type(2))) float f32x2;

#define INF_BITS 0x7F800000u

// ---------------------------------------------------------------------------
// prep: fp32 -> bf16, h-norms (-0.5*||.||^2, fp32 exact), init min arrays.
// ---------------------------------------------------------------------------
__global__ __launch_bounds__(256) void ahd_prep(
    const float* __restrict__ s1, const float* __restrict__ s2,
    __hip_bfloat16* __restrict__ abf, __hip_bfloat16* __restrict__ bbf,
    float* __restrict__ xh, float* __restrict__ yh,
    unsigned int* __restrict__ rmin, unsigned int* __restrict__ cmin,
    int N, int M)
{
    const int t   = blockIdx.x * 256 + threadIdx.x;
    const int row = t >> 4;
    const int sub = t & 15;

    if (t < N)          rmin[t]     = INF_BITS;
    else if (t < N + M) cmin[t - N] = INF_BITS;

    const float* src; __hip_bfloat16* dst; float* nrm; int r;
    if (row < N)            { src = s1; dst = abf; nrm = xh; r = row; }
    else if (row < N + M)   { src = s2; dst = bbf; nrm = yh; r = row - N; }
    else return;

    const float4 v = *(const float4*)&src[(size_t)r * 64 + sub * 4];
    __hip_bfloat16 h0 = __float2bfloat16(v.x), h1 = __float2bfloat16(v.y);
    __hip_bfloat16 h2 = __float2bfloat16(v.z), h3 = __float2bfloat16(v.w);
    short4v sv = { *(short*)&h0, *(short*)&h1, *(short*)&h2, *(short*)&h3 };
    *(short4v*)&dst[(size_t)r * 64 + sub * 4] = sv;

    float ss = v.x * v.x + v.y * v.y + v.z * v.z + v.w * v.w;
    ss += __shfl_xor(ss, 1);
    ss += __shfl_xor(ss, 2);
    ss += __shfl_xor(ss, 4);
    ss += __shfl_xor(ss, 8);
    if (sub == 0) nrm[r] = -0.5f * ss;     // fold: MFMA C-init = xh + yh
}

// ---------------------------------------------------------------------------
// fused distance-GEMM + row/col min. R12 structure (96us, VALU-bound at 63%),
// leaned out on BOTH remaining axes:
//  * occupancy: ldsA DROPPED -- A rows are wave-exclusive, frags loaded
//    straight from global (no broadcast redundancy). LDS 34.8K -> 18K
//    = 8 blocks/CU candidate (R12 was LDS-capped at 4).
//  * VALU count: c-init as f32x2 adds (v_pk_add_f32, 16->8/tile), col-min
//    tree in v_max3 shape (14->8/tile), swizzled B offsets hoisted
//    (swz(o + k*4096) == swz(o) + k*4096: XOR touches bits 6:4 only).
// B stays block-deduped via global_load_lds + involution (R12's key fix);
// 2D grid, NO XCD swizzle (spread B-strip broadcasts over all 8 L2s).
// ---------------------------------------------------------------------------
__global__ __launch_bounds__(256) void ahd_gemm(
    const __hip_bfloat16* __restrict__ abf, const __hip_bfloat16* __restrict__ bbf,
    const float* __restrict__ xh, const float* __restrict__ yh,
    unsigned int* __restrict__ rmin, unsigned int* __restrict__ cmin)
{
    __shared__ __attribute__((aligned(128))) char ldsB[16384];
    __shared__ float colbuf[4][128];

    const int tid  = threadIdx.x;
    const int lane = tid & 63;
    const int w    = tid >> 6;
    const int lr   = lane & 15, lh = lane >> 4;

    const int brow = blockIdx.x * 128;
    const int bcol = blockIdx.y * 128;

    // ---- stage B only (16 KB): linear LDS dest + inverse-swizzled source
    const char* bT = (const char*)bbf + (size_t)bcol * 128;
    #pragma unroll
    for (int it = 0; it < 4; ++it) {
        const int dst = w * 1024 + it * 4096;
        const int o   = dst + lane * 16;
        const int so  = o ^ ((o >> 3) & 0x70);
        __builtin_amdgcn_global_load_lds(
            (const __attribute__((address_space(1))) void*)(bT + so),
            (__attribute__((address_space(3))) void*)(ldsB + dst), 16, 0, 0);
    }

    // ---- A fragments straight from global (wave-exclusive rows, L2-hot)
    const char* aB = (const char*)abf + (size_t)(brow + w * 32 + lr) * 128 + lh * 16;
    const short8 aK0M0 = *(const short8*)(aB);
    const short8 aK1M0 = *(const short8*)(aB + 64);
    const short8 aK0M1 = *(const short8*)(aB + 2048);
    const short8 aK1M1 = *(const short8*)(aB + 2048 + 64);

    // ---- norms into named regs while staging is in flight
    const f32x4 xv0 = *(const f32x4*)&xh[brow + w * 32 + lh * 4];
    const f32x4 xv1 = *(const f32x4*)&xh[brow + w * 32 + 16 + lh * 4];
    const f32x2 xq0lo = {xv0[0], xv0[1]}, xq0hi = {xv0[2], xv0[3]};
    const f32x2 xq1lo = {xv1[0], xv1[1]}, xq1hi = {xv1[2], xv1[3]};
    const float yv0 = yh[bcol + lr];
    const float yv1 = yh[bcol + 16 + lr];
    const float yv2 = yh[bcol + 32 + lr];
    const float yv3 = yh[bcol + 48 + lr];
    const float yv4 = yh[bcol + 64 + lr];
    const float yv5 = yh[bcol + 80 + lr];
    const float yv6 = yh[bcol + 96 + lr];
    const float yv7 = yh[bcol + 112 + lr];

    __syncthreads();   // drains B staging; the ONLY barrier before col flush

    // ---- hoisted swizzled B-frag base offsets (tile stride +4096 is exact
    //      in swizzled space: the XOR reads bits 9:7, writes bits 6:4)
    int ob00 = lr * 128 + lh * 16;              ob00 ^= (ob00 >> 3) & 0x70;
    int ob01 = lr * 128 + 64 + lh * 16;         ob01 ^= (ob01 >> 3) & 0x70;
    int ob10 = (16 + lr) * 128 + lh * 16;       ob10 ^= (ob10 >> 3) & 0x70;
    int ob11 = (16 + lr) * 128 + 64 + lh * 16;  ob11 ^= (ob11 >> 3) & 0x70;

    f32x4 rowm0 = {-1e30f, -1e30f, -1e30f, -1e30f};   // MAX accumulators
    f32x4 rowm1 = {-1e30f, -1e30f, -1e30f, -1e30f};

    // one 32-col tile pair (n-frags N0, N0+1); all offsets compile-time static
#define AHD_TILE(N0, YA, YB)                                                   \
    {                                                                          \
        const short8 b00 = *(const short8*)(ldsB + ob00 + (N0) * 2048);        \
        const short8 b01 = *(const short8*)(ldsB + ob01 + (N0) * 2048);        \
        const short8 b10 = *(const short8*)(ldsB + ob10 + (N0) * 2048);        \
        const short8 b11 = *(const short8*)(ldsB + ob11 + (N0) * 2048);        \
        const f32x2 ya2 = {(YA), (YA)}, yb2 = {(YB), (YB)};                    \
        const f32x2 p0 = xq0lo + ya2, p1 = xq0hi + ya2;  /* v_pk_add_f32 */    \
        const f32x2 q0 = xq0lo + yb2, q1 = xq0hi + yb2;                        \
        const f32x2 r0 = xq1lo + ya2, r1 = xq1hi + ya2;                        \
        const f32x2 s0 = xq1lo + yb2, s1 = xq1hi + yb2;                        \
        f32x4 c00 = {p0.x, p0.y, p1.x, p1.y};                                  \
        f32x4 c01 = {q0.x, q0.y, q1.x, q1.y};                                  \
        f32x4 c10 = {r0.x, r0.y, r1.x, r1.y};                                  \
        f32x4 c11 = {s0.x, s0.y, s1.x, s1.y};                                  \
        c00 = __builtin_amdgcn_mfma_f32_16x16x32_bf16(aK0M0, b00, c00, 0, 0, 0); \
        c01 = __builtin_amdgcn_mfma_f32_16x16x32_bf16(aK0M0, b10, c01, 0, 0, 0); \
        c10 = __builtin_amdgcn_mfma_f32_16x16x32_bf16(aK0M1, b00, c10, 0, 0, 0); \
        c11 = __builtin_amdgcn_mfma_f32_16x16x32_bf16(aK0M1, b10, c11, 0, 0, 0); \
        c00 = __builtin_amdgcn_mfma_f32_16x16x32_bf16(aK1M0, b01, c00, 0, 0, 0); \
        c01 = __builtin_amdgcn_mfma_f32_16x16x32_bf16(aK1M0, b11, c01, 0, 0, 0); \
        c10 = __builtin_amdgcn_mfma_f32_16x16x32_bf16(aK1M1, b01, c10, 0, 0, 0); \
        c11 = __builtin_amdgcn_mfma_f32_16x16x32_bf16(aK1M1, b11, c11, 0, 0, 0); \
        rowm0[0] = fmaxf(fmaxf(c00[0], c01[0]), rowm0[0]);   /* v_max3 */      \
        rowm0[1] = fmaxf(fmaxf(c00[1], c01[1]), rowm0[1]);                     \
        rowm0[2] = fmaxf(fmaxf(c00[2], c01[2]), rowm0[2]);                     \
        rowm0[3] = fmaxf(fmaxf(c00[3], c01[3]), rowm0[3]);                     \
        rowm1[0] = fmaxf(fmaxf(c10[0], c11[0]), rowm1[0]);                     \
        rowm1[1] = fmaxf(fmaxf(c10[1], c11[1]), rowm1[1]);                     \
        rowm1[2] = fmaxf(fmaxf(c10[2], c11[2]), rowm1[2]);                     \
        rowm1[3] = fmaxf(fmaxf(c10[3], c11[3]), rowm1[3]);                     \
        const float u0 = fmaxf(fmaxf(c00[0], c00[1]), c00[2]);  /* v_max3 */   \
        const float u1 = fmaxf(fmaxf(c00[3], c10[0]), c10[1]);                 \
        const float u2 = fmaxf(c10[2], c10[3]);                               \
        float cm0 = fmaxf(fmaxf(u0, u1), u2);                                  \
        const float t0 = fmaxf(fmaxf(c01[0], c01[1]), c01[2]);                 \
        const float t1 = fmaxf(fmaxf(c01[3], c11[0]), c11[1]);                 \
        const float t2 = fmaxf(c11[2], c11[3]);                               \
        float cm1 = fmaxf(fmaxf(t0, t1), t2);                                  \
        cm0 = fmaxf(cm0, __shfl_xor(cm0, 16));                                 \
        cm0 = fmaxf(cm0, __shfl_xor(cm0, 32));                                 \
        cm1 = fmaxf(cm1, __shfl_xor(cm1, 16));                                 \
        cm1 = fmaxf(cm1, __shfl_xor(cm1, 32));                                 \
        if (lh == 0) {                                                         \
            colbuf[w][(N0) * 16 + lr]      = cm0;                              \
            colbuf[w][(N0) * 16 + 16 + lr] = cm1;                              \
        }                                                                      \
    }

    AHD_TILE(0, yv0, yv1)
    AHD_TILE(2, yv2, yv3)
    AHD_TILE(4, yv4, yv5)
    AHD_TILE(6, yv6, yv7)
#undef AHD_TILE

    // ---- row flush: rows wave-exclusive; reduce across the 16 lr lanes
    #pragma unroll
    for (int m = 0; m < 2; ++m)
        #pragma unroll
        for (int j = 0; j < 4; ++j) {
            float v = m ? rowm1[j] : rowm0[j];
            v = fmaxf(v, __shfl_xor(v, 1));
            v = fmaxf(v, __shfl_xor(v, 2));
            v = fmaxf(v, __shfl_xor(v, 4));
            v = fmaxf(v, __shfl_xor(v, 8));
            if (lr == 0) {
                const int row = brow + w * 32 + m * 16 + lh * 4 + j;
                const float d2 = fmaxf(-2.f * v, 0.f);
                atomicMin(&rmin[row], __float_as_uint(d2));   // fire-and-forget
            }
        }

    __syncthreads();   // colbuf slices complete

    // ---- col flush: merge the 4 wave slices, 1 col per thread (tid<128)
    if (tid < 128) {
        const float v = fmaxf(fmaxf(colbuf[0][tid], colbuf[1][tid]),
                              fmaxf(colbuf[2][tid], colbuf[3][tid]));
        const float d2 = fmaxf(-2.f * v, 0.f);
        atomicMin(&cmin[bcol + tid], __float_as_uint(d2));
    }
}

// ---------------------------------------------------------------------------
// finalize: out = mean(sqrt(rmin)) + mean(sqrt(cmin)); 1024 thr, uint4 loads.
// ---------------------------------------------------------------------------
__global__ __launch_bounds__(1024) void ahd_finalize(
    const unsigned int* __restrict__ rmin, const unsigned int* __restrict__ cmin,
    float* __restrict__ out, int N, int M)
{
    const int tid = threadIdx.x;
    const uint4* r4 = (const uint4*)rmin;
    const uint4* c4 = (const uint4*)cmin;
    float sa = 0.f, sb = 0.f;
    for (int i = tid; i < (N >> 2); i += 1024) {
        const uint4 v = r4[i];
        sa += sqrtf(__uint_as_float(v.x)) + sqrtf(__uint_as_float(v.y))
            + sqrtf(__uint_as_float(v.z)) + sqrtf(__uint_as_float(v.w));
    }
    for (int i = tid; i < (M >> 2); i += 1024) {
        const uint4 v = c4[i];
        sb += sqrtf(__uint_as_float(v.x)) + sqrtf(__uint_as_float(v.y))
            + sqrtf(__uint_as_float(v.z)) + sqrtf(__uint_as_float(v.w));
    }
    float v = sa / (float)N + sb / (float)M;
    #pragma unroll
    for (int s = 1; s < 64; s <<= 1) v += __shfl_xor(v, s);
    __shared__ float red[16];
    if ((tid & 63) == 0) red[tid >> 6] = v;
    __syncthreads();
    if (tid == 0) {
        float t = 0.f;
        #pragma unroll
        for (int i = 0; i < 16; ++i) t += red[i];
        out[0] = t;
    }
}

extern "C" void kernel_launch(void* const* d_in, const int* in_sizes, int n_in,
                              void* d_out, int out_size, void* d_ws, size_t ws_size,
                              hipStream_t stream) {
    const float* s1 = (const float*)d_in[0];
    const float* s2 = (const float*)d_in[1];
    const int N = in_sizes[0] / 64;
    const int M = in_sizes[1] / 64;

    char* ws = (char*)d_ws;
    __hip_bfloat16* abf = (__hip_bfloat16*)ws;
    __hip_bfloat16* bbf = (__hip_bfloat16*)(ws + (size_t)N * 128);
    float* xh = (float*)(ws + (size_t)(N + M) * 128);
    float* yh = xh + N;
    unsigned int* rmin = (unsigned int*)(yh + M);
    unsigned int* cmin = rmin + N;

    const int prows = ((N + M) * 16 + 255) / 256;
    ahd_prep<<<prows, 256, 0, stream>>>(s1, s2, abf, bbf, xh, yh,
                                        rmin, cmin, N, M);
    dim3 grid(N / 128, M / 128);    // x = row-tiles fastest; NO XCD swizzle
    ahd_gemm<<<grid, 256, 0, stream>>>(abf, bbf, xh, yh, rmin, cmin);
    ahd_finalize<<<1, 1024, 0, stream>>>(rmin, cmin, (float*)d_out, N, M);
}

// Round 14
// 97.926 us; speedup vs baseline: 1.0421x; 1.0421x over previous
//
#include <hip/hip_runtime.h>
#include <hip/hip_bf16.h>

typedef __attribute__((ext_vector_type(8))) short short8;  // 8 bf16 (4 VGPRs)
typedef __attribute__((ext_vector_type(4))) short short4v;
typedef __attribute__((ext_vector_type(4))) float f32x4;
typedef __attribute__((ext_vector_type(2))) float f32x2;

#define INF_BITS 0x7F800000u

// ---------------------------------------------------------------------------
// prep: fp32 -> bf16, h-norms (-0.5*||.||^2, fp32 exact), init min arrays.
// ---------------------------------------------------------------------------
__global__ __launch_bounds__(256) void ahd_prep(
    const float* __restrict__ s1, const float* __restrict__ s2,
    __hip_bfloat16* __restrict__ abf, __hip_bfloat16* __restrict__ bbf,
    float* __restrict__ xh, float* __restrict__ yh,
    unsigned int* __restrict__ rmin, unsigned int* __restrict__ cmin,
    int N, int M)
{
    const int t   = blockIdx.x * 256 + threadIdx.x;
    const int row = t >> 4;
    const int sub = t & 15;

    if (t < N)          rmin[t]     = INF_BITS;
    else if (t < N + M) cmin[t - N] = INF_BITS;

    const float* src; __hip_bfloat16* dst; float* nrm; int r;
    if (row < N)            { src = s1; dst = abf; nrm = xh; r = row; }
    else if (row < N + M)   { src = s2; dst = bbf; nrm = yh; r = row - N; }
    else return;

    const float4 v = *(const float4*)&src[(size_t)r * 64 + sub * 4];
    __hip_bfloat16 h0 = __float2bfloat16(v.x), h1 = __float2bfloat16(v.y);
    __hip_bfloat16 h2 = __float2bfloat16(v.z), h3 = __float2bfloat16(v.w);
    short4v sv = { *(short*)&h0, *(short*)&h1, *(short*)&h2, *(short*)&h3 };
    *(short4v*)&dst[(size_t)r * 64 + sub * 4] = sv;

    float ss = v.x * v.x + v.y * v.y + v.z * v.z + v.w * v.w;
    ss += __shfl_xor(ss, 1);
    ss += __shfl_xor(ss, 2);
    ss += __shfl_xor(ss, 4);
    ss += __shfl_xor(ss, 8);
    if (sub == 0) nrm[r] = -0.5f * ss;     // fold: MFMA C-init = xh + yh
}

// ---------------------------------------------------------------------------
// fused distance-GEMM + row/col min. R13 base (96us) with the two per-WAVE
// costs attacked (R13 lesson: VALU-count cut gave 0; flush ~35% + fixed ~20%
// of wave time are the stall sources):
//  * wave tile 2x: 64 rows x 128 cols (block 256x128, grid 8192) -- staging,
//    prologue, B ds_reads, col flush per element all halve. m-frags SEQUENCED
//    through one transient c-pair, live set ~110 VGPR, no forced bounds.
//  * row flush: LDS TRANSPOSE instead of 4-round shfl: xor8 pre-reduce,
//    conflict-free pad-17 rowbuf, then each of 256 threads owns ONE row
//    (8 reads + 7 max + 1 atomic). Replaces 64 shfl+64 max per wave.
// B stays block-deduped via global_load_lds + involution; 2D grid, NO XCD
// swizzle. C-init fold throughout (min d^2 == max acc).
// ---------------------------------------------------------------------------
__global__ __launch_bounds__(256) void ahd_gemm(
    const __hip_bfloat16* __restrict__ abf, const __hip_bfloat16* __restrict__ bbf,
    const float* __restrict__ xh, const float* __restrict__ yh,
    unsigned int* __restrict__ rmin, unsigned int* __restrict__ cmin)
{
    __shared__ __attribute__((aligned(128))) char ldsB[16384];
    __shared__ float rowbuf[4][4][8][17];   // [w][lh][lr<8][j16 +pad] = 8704 B
    __shared__ float colbuf[4][128];

    const int tid  = threadIdx.x;
    const int lane = tid & 63;
    const int w    = tid >> 6;
    const int lr   = lane & 15, lh = lane >> 4;   // lh in 0..3

    const int brow = blockIdx.x * 256;
    const int bcol = blockIdx.y * 128;

    // ---- stage B (16 KB): linear LDS dest + inverse-swizzled source
    const char* bT = (const char*)bbf + (size_t)bcol * 128;
    #pragma unroll
    for (int it = 0; it < 4; ++it) {
        const int dst = w * 1024 + it * 4096;
        const int o   = dst + lane * 16;
        const int so  = o ^ ((o >> 3) & 0x70);
        __builtin_amdgcn_global_load_lds(
            (const __attribute__((address_space(1))) void*)(bT + so),
            (__attribute__((address_space(3))) void*)(ldsB + dst), 16, 0, 0);
    }

    // ---- A fragments straight from global (wave-exclusive 64 rows, L2-hot)
    const char* aB = (const char*)abf + (size_t)(brow + w * 64 + lr) * 128 + lh * 16;
    short8 afr[2][4];   // [ks][m]
    #pragma unroll
    for (int m = 0; m < 4; ++m) {
        afr[0][m] = *(const short8*)(aB + m * 2048);
        afr[1][m] = *(const short8*)(aB + m * 2048 + 64);
    }

    // ---- norms while staging is in flight
    f32x2 xqlo[4], xqhi[4];
    #pragma unroll
    for (int m = 0; m < 4; ++m) {
        const f32x4 xv = *(const f32x4*)&xh[brow + w * 64 + m * 16 + lh * 4];
        xqlo[m] = (f32x2){xv[0], xv[1]};
        xqhi[m] = (f32x2){xv[2], xv[3]};
    }
    const float yv0 = yh[bcol + lr];
    const float yv1 = yh[bcol + 16 + lr];
    const float yv2 = yh[bcol + 32 + lr];
    const float yv3 = yh[bcol + 48 + lr];
    const float yv4 = yh[bcol + 64 + lr];
    const float yv5 = yh[bcol + 80 + lr];
    const float yv6 = yh[bcol + 96 + lr];
    const float yv7 = yh[bcol + 112 + lr];

    __syncthreads();   // drains B staging

    // ---- hoisted swizzled B-frag base offsets (+2048 per n-frag is exact in
    //      swizzled space: XOR reads bits 9:7, writes 6:4)
    int ob00 = lr * 128 + lh * 16;              ob00 ^= (ob00 >> 3) & 0x70;
    int ob01 = lr * 128 + 64 + lh * 16;         ob01 ^= (ob01 >> 3) & 0x70;
    int ob10 = (16 + lr) * 128 + lh * 16;       ob10 ^= (ob10 >> 3) & 0x70;
    int ob11 = (16 + lr) * 128 + 64 + lh * 16;  ob11 ^= (ob11 >> 3) & 0x70;

    f32x4 rowm[4];
    #pragma unroll
    for (int m = 0; m < 4; ++m) rowm[m] = (f32x4){-1e30f, -1e30f, -1e30f, -1e30f};

    // one 32-col tile pair (n-frags N0, N0+1); m-frags sequenced (transient c)
#define AHD_TILE(N0, YA, YB)                                                   \
    {                                                                          \
        const short8 b00 = *(const short8*)(ldsB + ob00 + (N0) * 2048);        \
        const short8 b01 = *(const short8*)(ldsB + ob01 + (N0) * 2048);        \
        const short8 b10 = *(const short8*)(ldsB + ob10 + (N0) * 2048);        \
        const short8 b11 = *(const short8*)(ldsB + ob11 + (N0) * 2048);        \
        const f32x2 ya2 = {(YA), (YA)}, yb2 = {(YB), (YB)};                    \
        float cm0 = -1e30f, cm1 = -1e30f;                                      \
        _Pragma("unroll")                                                      \
        for (int m = 0; m < 4; ++m) {                                          \
            const f32x2 p0 = xqlo[m] + ya2, p1 = xqhi[m] + ya2;                \
            const f32x2 q0 = xqlo[m] + yb2, q1 = xqhi[m] + yb2;                \
            f32x4 c0 = {p0.x, p0.y, p1.x, p1.y};                               \
            f32x4 c1 = {q0.x, q0.y, q1.x, q1.y};                               \
            c0 = __builtin_amdgcn_mfma_f32_16x16x32_bf16(afr[0][m], b00, c0, 0, 0, 0); \
            c1 = __builtin_amdgcn_mfma_f32_16x16x32_bf16(afr[0][m], b10, c1, 0, 0, 0); \
            c0 = __builtin_amdgcn_mfma_f32_16x16x32_bf16(afr[1][m], b01, c0, 0, 0, 0); \
            c1 = __builtin_amdgcn_mfma_f32_16x16x32_bf16(afr[1][m], b11, c1, 0, 0, 0); \
            rowm[m][0] = fmaxf(fmaxf(c0[0], c1[0]), rowm[m][0]);   /* max3 */  \
            rowm[m][1] = fmaxf(fmaxf(c0[1], c1[1]), rowm[m][1]);               \
            rowm[m][2] = fmaxf(fmaxf(c0[2], c1[2]), rowm[m][2]);               \
            rowm[m][3] = fmaxf(fmaxf(c0[3], c1[3]), rowm[m][3]);               \
            cm0 = fmaxf(fmaxf(fmaxf(c0[0], c0[1]), fmaxf(c0[2], c0[3])), cm0); \
            cm1 = fmaxf(fmaxf(fmaxf(c1[0], c1[1]), fmaxf(c1[2], c1[3])), cm1); \
        }                                                                      \
        cm0 = fmaxf(cm0, __shfl_xor(cm0, 16));                                 \
        cm0 = fmaxf(cm0, __shfl_xor(cm0, 32));                                 \
        cm1 = fmaxf(cm1, __shfl_xor(cm1, 16));                                 \
        cm1 = fmaxf(cm1, __shfl_xor(cm1, 32));                                 \
        if (lh == 0) {                                                         \
            colbuf[w][(N0) * 16 + lr]      = cm0;                              \
            colbuf[w][(N0) * 16 + 16 + lr] = cm1;                              \
        }                                                                      \
    }

    AHD_TILE(0, yv0, yv1)
    AHD_TILE(2, yv2, yv3)
    AHD_TILE(4, yv4, yv5)
    AHD_TILE(6, yv6, yv7)
#undef AHD_TILE

    // ---- row partials: xor8 pre-reduce, conflict-free transpose into rowbuf
    #pragma unroll
    for (int m = 0; m < 4; ++m)
        #pragma unroll
        for (int j = 0; j < 4; ++j) {
            float v = rowm[m][j];
            v = fmaxf(v, __shfl_xor(v, 8));
            if (lr < 8) rowbuf[w][lh][lr][m * 4 + j] = v;
        }

    __syncthreads();   // rowbuf + colbuf complete

    // ---- row flush: each thread owns ONE of the block's 256 rows
    {
        const int rw = tid >> 6, rr = tid & 63;
        const int rm = rr >> 4, rlh = (rr >> 2) & 3, rj = rr & 3;
        const float* p = &rowbuf[rw][rlh][0][rm * 4 + rj];
        float v = p[0];
        v = fmaxf(v, p[17]);
        v = fmaxf(v, p[2 * 17]);
        v = fmaxf(v, p[3 * 17]);
        v = fmaxf(v, p[4 * 17]);
        v = fmaxf(v, p[5 * 17]);
        v = fmaxf(v, p[6 * 17]);
        v = fmaxf(v, p[7 * 17]);
        const float d2 = fmaxf(-2.f * v, 0.f);
        atomicMin(&rmin[brow + tid], __float_as_uint(d2));
    }

    // ---- col flush: merge the 4 wave slices, 1 col per thread (tid<128)
    if (tid < 128) {
        const float v = fmaxf(fmaxf(colbuf[0][tid], colbuf[1][tid]),
                              fmaxf(colbuf[2][tid], colbuf[3][tid]));
        const float d2 = fmaxf(-2.f * v, 0.f);
        atomicMin(&cmin[bcol + tid], __float_as_uint(d2));
    }
}

// ---------------------------------------------------------------------------
// finalize: out = mean(sqrt(rmin)) + mean(sqrt(cmin)); 1024 thr, uint4 loads.
// ---------------------------------------------------------------------------
__global__ __launch_bounds__(1024) void ahd_finalize(
    const unsigned int* __restrict__ rmin, const unsigned int* __restrict__ cmin,
    float* __restrict__ out, int N, int M)
{
    const int tid = threadIdx.x;
    const uint4* r4 = (const uint4*)rmin;
    const uint4* c4 = (const uint4*)cmin;
    float sa = 0.f, sb = 0.f;
    for (int i = tid; i < (N >> 2); i += 1024) {
        const uint4 v = r4[i];
        sa += sqrtf(__uint_as_float(v.x)) + sqrtf(__uint_as_float(v.y))
            + sqrtf(__uint_as_float(v.z)) + sqrtf(__uint_as_float(v.w));
    }
    for (int i = tid; i < (M >> 2); i += 1024) {
        const uint4 v = c4[i];
        sb += sqrtf(__uint_as_float(v.x)) + sqrtf(__uint_as_float(v.y))
            + sqrtf(__uint_as_float(v.z)) + sqrtf(__uint_as_float(v.w));
    }
    float v = sa / (float)N + sb / (float)M;
    #pragma unroll
    for (int s = 1; s < 64; s <<= 1) v += __shfl_xor(v, s);
    __shared__ float red[16];
    if ((tid & 63) == 0) red[tid >> 6] = v;
    __syncthreads();
    if (tid == 0) {
        float t = 0.f;
        #pragma unroll
        for (int i = 0; i < 16; ++i) t += red[i];
        out[0] = t;
    }
}

extern "C" void kernel_launch(void* const* d_in, const int* in_sizes, int n_in,
                              void* d_out, int out_size, void* d_ws, size_t ws_size,
                              hipStream_t stream) {
    const float* s1 = (const float*)d_in[0];
    const float* s2 = (const float*)d_in[1];
    const int N = in_sizes[0] / 64;
    const int M = in_sizes[1] / 64;

    char* ws = (char*)d_ws;
    __hip_bfloat16* abf = (__hip_bfloat16*)ws;
    __hip_bfloat16* bbf = (__hip_bfloat16*)(ws + (size_t)N * 128);
    float* xh = (float*)(ws + (size_t)(N + M) * 128);
    float* yh = xh + N;
    unsigned int* rmin = (unsigned int*)(yh + M);
    unsigned int* cmin = rmin + N;

    const int prows = ((N + M) * 16 + 255) / 256;
    ahd_prep<<<prows, 256, 0, stream>>>(s1, s2, abf, bbf, xh, yh,
                                        rmin, cmin, N, M);
    dim3 grid(N / 256, M / 128);    // 8192 blocks; x fastest; NO XCD swizzle
    ahd_gemm<<<grid, 256, 0, stream>>>(abf, bbf, xh, yh, rmin, cmin);
    ahd_finalize<<<1, 1024, 0, stream>>>(rmin, cmin, (float*)d_out, N, M);
}